// Round 1
// baseline (209.554 us; speedup 1.0000x reference)
//
#include <hip/hip_runtime.h>
#include <math.h>

#define A_TOT  36864
#define N_IMG  32
#define M_GT   32
#define TOTAL_K 256
#define MAX_FG_K 128
#define NCHUNK 144          // chunks (256 anchors) per image
#define CAP    1024
#define PAIR_CAP 2048
#define FGB    32
#define BGB    64
#define RAW_NEG1 ((int)0xBF800000u)   // __float_as_int(-1.0f)
#define RAW_P07  ((int)0x3F333333u)   // __float_as_int(0.7f)
#define RAW_P03  ((int)0x3E99999Au)   // __float_as_int(0.3f)
#define INT_MINV ((int)0x80000000u)
#define TT 512
#define NWAVE 8
// IoU values live in {-1.0} ∪ [0,1]; signed-int compare of raw float bits ==
// float compare on that domain (no -0.0/NaN on the valid path).
// flags layout: bid[0:4] | fg<<5 | bg<<6 | bin<<7 (10b)
// (bg bit may stay set on fg-promoted anchors; consumers use bg & !fg)

__device__ __forceinline__ int bin_of(float r){
    int b = (int)(r * 1024.0f);
    return b > 1023 ? 1023 : (b < 0 ? 0 : b);
}

struct Pred { float x1,y1,x2,y2,area; int valid; };

__device__ __forceinline__ Pred mk_pred(float4 a, float4 d){
#pragma clang fp contract(off)
    Pred p;
    float w  = a.z - a.x + 1.0f;
    float h  = a.w - a.y + 1.0f;
    float cx = a.x + 0.5f*w;
    float cy = a.y + 0.5f*h;
    float pcx = d.x*w + cx;
    float pcy = d.y*h + cy;
    float pw = (float)exp((double)d.z) * w;
    float ph = (float)exp((double)d.w) * h;
    p.x1 = pcx - 0.5f*pw;
    p.y1 = pcy - 0.5f*ph;
    p.x2 = pcx + 0.5f*pw;
    p.y2 = pcy + 0.5f*ph;
    p.valid = (p.x1 >= 0.0f) && (p.y1 >= 0.0f) && (p.x2 < 1024.0f) && (p.y2 < 1024.0f);
    p.area  = (p.x2 - p.x1 + 1.0f) * (p.y2 - p.y1 + 1.0f);
    return p;
}

__device__ __forceinline__ float gt_area(float4 g){
#pragma clang fp contract(off)
    return (g.z - g.x + 1.0f) * (g.w - g.y + 1.0f);
}

__device__ __forceinline__ float iou_val(const Pred& p, float gx1, float gy1,
                                         float gx2, float gy2, float ga){
#pragma clang fp contract(off)
    float iw = fminf(p.x2,gx2) - fmaxf(p.x1,gx1) + 1.0f; iw = iw < 0.0f ? 0.0f : iw;
    float ih = fminf(p.y2,gy2) - fmaxf(p.y1,gy1) + 1.0f; ih = ih < 0.0f ? 0.0f : ih;
    float inter = iw * ih;
    float uni = (p.area + ga) - inter;
    float v = inter / uni;
    return p.valid ? v : -1.0f;
}

__device__ __forceinline__ void coeff_fn(float4 a, float4 g, float cf[4]){
#pragma clang fp contract(off)
    float aw = a.z - a.x + 1.0f, ah = a.w - a.y + 1.0f;
    float acx = a.x + 0.5f*aw,  acy = a.y + 0.5f*ah;
    float gw = g.z - g.x + 1.0f, gh = g.w - g.y + 1.0f;
    float gcx = g.x + 0.5f*gw,  gcy = g.y + 0.5f*gh;
    cf[0] = (gcx - acx) / aw;
    cf[1] = (gcy - acy) / ah;
    cf[2] = (float)log((double)(gw / aw));
    cf[3] = (float)log((double)(gh / ah));
}

// ---------- K1: heavy pass. Flags (fg=thrfg), bmax, pgm via atomicMax straight
// ---------- over 0xAA poison (poison < raw(-1)). Hist atomics REMOVED — the
// ---------- tail kernel rebuilds the histogram in LDS from final flags. -------
__global__ void k_main(const float* __restrict__ anchors, const float* __restrict__ gt,
                       const float* __restrict__ dl, const float* __restrict__ rs,
                       int* __restrict__ bmax, int* __restrict__ flagsA,
                       int* __restrict__ pgm){
    int blk = blockIdx.x;
    int n = blk / NCHUNK, ch = blk % NCHUNK;
    int tid = threadIdx.x;
    int a = ch*256 + tid;
    __shared__ float4 sgt[M_GT];
    __shared__ float  sga[M_GT];
    __shared__ int    sbm[M_GT];
    if(tid < M_GT){
        float4 g = ((const float4*)gt)[n*M_GT + tid];
        sgt[tid] = g; sga[tid] = gt_area(g); sbm[tid] = RAW_NEG1;
    }
    __syncthreads();
    float4 anc = ((const float4*)anchors)[a];
    float4 d   = ((const float4*)dl)[(long)n*A_TOT + a];
    Pred p = mk_pred(anc, d);
    int beste = INT_MINV, bid = 0;
    int mm0 = tid & 31;
    #pragma unroll
    for(int j=0;j<M_GT;++j){
        int m = (mm0 + j) & 31;      // stagger: 2-way same-address LDS atomic (free)
        float4 g = sgt[m];
        float v = iou_val(p, g.x, g.y, g.z, g.w, sga[m]);
        int vi = __float_as_int(v);
        atomicMax(&sbm[m], vi);
        // rotated visit order => explicit (v desc, m asc) tie-break == first argmax
        if(vi > beste || (vi == beste && m < bid)){ beste = vi; bid = m; }
    }
    __syncthreads();
    long ia = (long)n*A_TOT + a;
    int bin = bin_of(rs[ia]);
    int thrfg = (beste >= RAW_P07) ? 1 : 0;
    int bg0 = (!thrfg) & (beste < RAW_P03 ? 1 : 0) & p.valid;
    flagsA[ia] = bid | (thrfg<<5) | (bg0<<6) | (bin<<7);
    if(tid < M_GT){
        bmax[blk*M_GT + tid] = sbm[tid];
        atomicMax(&pgm[n*M_GT + tid], sbm[tid]);   // poison 0xAAAAAAAA < raw(-1): no init needed
    }
}

// ---------- K2: fused tail. One block per image: abox fix, LDS histogram,
// ---------- quota, boundary candidates+ranking (LDS), compaction, emit.
// ---------- All intermediates in LDS; global flagsA is only modified in the
// ---------- fix phase (before any plain load in this kernel), so no L1
// ---------- staleness. Rank-keeps go to an LDS bitmap instead of KEEPB. ------
__global__ __launch_bounds__(TT) void k_tail(
        const float* __restrict__ anchors, const float* __restrict__ gt,
        const float* __restrict__ dl, const float* __restrict__ rs,
        const int* __restrict__ bmax, const int* __restrict__ pgm,
        int* __restrict__ flagsA, float* __restrict__ out){
    int n = blockIdx.x;
    int tid = threadIdx.x;
    int wave = tid >> 6, lane = tid & 63;

    __shared__ float4 s_gt[M_GT];
    __shared__ float  s_ga[M_GT];
    __shared__ int    s_pgm[M_GT];
    __shared__ int    s_pairs[PAIR_CAP];
    __shared__ int    s_np;
    __shared__ __align__(16) int s_hist[2048];       // fg | bg histograms
    __shared__ unsigned int s_bitmap[A_TOT/32];      // rank-keep bitmap (4.6 KB)
    __shared__ unsigned long long s_ckey[2*CAP];     // 16 KB
    __shared__ int s_cc[2];
    __shared__ int s_chunk[NCHUNK];
    __shared__ int s_cbase[NCHUNK];
    __shared__ int s_scan[256];
    __shared__ int s_q[4];
    __shared__ int s_m0;

    if(tid < M_GT){
        float4 g = ((const float4*)gt)[n*M_GT + tid];
        s_gt[tid] = g; s_ga[tid] = gt_area(g); s_pgm[tid] = pgm[n*M_GT + tid];
    }
    if(tid == 0) s_np = 0;
    if(tid < 2) s_cc[tid] = 0;
    for(int i=tid; i<2048; i+=TT) s_hist[i] = 0;
    for(int i=tid; i<A_TOT/32; i+=TT) s_bitmap[i] = 0u;
    __syncthreads();

    // ---- Phase A: abox fix. Collect (chunk,gt) pairs with bmax==pgm, then
    // ---- recompute those chunks vs that gt; promote bit-exact achievers. ----
    for(int i=tid; i<NCHUNK*M_GT; i+=TT){       // bmax layout => coalesced
        int ch = i >> 5, m = i & 31;
        if(bmax[(n*NCHUNK + ch)*M_GT + m] == s_pgm[m]){
            int pos = atomicAdd(&s_np, 1);
            if(pos < PAIR_CAP) s_pairs[pos] = (ch<<5) | m;
        }
    }
    __syncthreads();
    int np = s_np; if(np > PAIR_CAP) np = PAIR_CAP;
    for(int i=tid; i<np*256; i+=TT){
        int pr = s_pairs[i>>8];
        int ch = pr >> 5, m = pr & 31;
        int a = ch*256 + (i & 255);
        long ia = (long)n*A_TOT + a;
        float4 anc = ((const float4*)anchors)[a];
        float4 d   = ((const float4*)dl)[ia];
        Pred p = mk_pred(anc, d);
        float4 g = s_gt[m];
        float v = iou_val(p, g.x, g.y, g.z, g.w, s_ga[m]);
        if(p.valid && __float_as_int(v) == s_pgm[m])
            atomicOr(&flagsA[ia], FGB);          // idempotent; pgm>=0 => achiever valid
    }
    __syncthreads();                              // drains atomics (vmcnt0 at barrier)

    // ---- Phase B: build histogram in LDS from FINAL flags (== old incremental
    // ---- hist + exactly-once repairs). Wave-per-chunk: coalesced 256B loads. --
    for(int ch=wave; ch<NCHUNK; ch+=NWAVE){
        for(int s=0; s<4; ++s){
            int a = ch*256 + s*64 + lane;
            int f = flagsA[(long)n*A_TOT + a];
            if(a == 0) s_m0 = f;                  // post-fix flags of anchor 0
            int fg = (f>>5)&1;
            int bg = ((f>>6)&1) & !fg;
            int bin = (f>>7)&1023;
            if(fg) atomicAdd(&s_hist[bin], 1);
            else if(bg) atomicAdd(&s_hist[1024 + bin], 1);
        }
    }
    __syncthreads();

    // ---- Phase B2: quota (k_bound logic verbatim, on LDS hist, once). -------
    int fgK = 0;
    for(int phase=0; phase<2; ++phase){
        int part = 0, b0 = 0; int4 h4 = {0,0,0,0};
        if(tid < 256){
            b0 = 1023 - 4*tid;                    // bins b0..b0-3 desc
            h4 = *(const int4*)&s_hist[phase*1024 + b0 - 3];
            part = h4.x + h4.y + h4.z + h4.w;
            s_scan[tid] = part;
        }
        __syncthreads();
        for(int off=1; off<256; off<<=1){
            int add = (tid<256 && tid>=off) ? s_scan[tid-off] : 0;
            __syncthreads();
            if(tid<256) s_scan[tid] += add;
            __syncthreads();
        }
        int total = s_scan[255];
        if(tid==0){ s_q[phase*2] = -1; s_q[phase*2+1] = 0; }
        __syncthreads();
        int quota = (phase==0) ? MAX_FG_K : (TOTAL_K - fgK);
        if(tid<256 && total > quota){
            int pre = s_scan[tid] - part, cum = pre;
            int hs4[4] = {h4.w, h4.z, h4.y, h4.x};        // descending bin order
            for(int j=0;j<4;++j){
                int hh = hs4[j];
                if(cum < quota && cum + hh >= quota){ s_q[phase*2] = b0-j; s_q[phase*2+1] = quota-cum; }
                cum += hh;
            }
        }
        __syncthreads();
        if(phase==0) fgK = (total < MAX_FG_K) ? total : MAX_FG_K;
    }
    int bs0 = s_q[0], bs1 = s_q[2];

    // ---- Phase C: sure counts per chunk + boundary candidates into LDS. -----
    for(int ch=wave; ch<NCHUNK; ch+=NWAVE){
        int scnt = 0;
        for(int s=0; s<4; ++s){
            int a = ch*256 + s*64 + lane;
            long ia = (long)n*A_TOT + a;
            int f = flagsA[ia];                   // L1-hot from phase B
            int fg = (f>>5)&1;
            int bg = ((f>>6)&1) & !fg;
            int bin = (f>>7)&1023;
            int sure = 0;
            if(fg | bg){
                int c = fg ? 0 : 1;
                int bsel = fg ? bs0 : bs1;
                if(bin > bsel) sure = 1;          // keepAll encoded as bsel=-1
                else if(bin == bsel){
                    int pos = atomicAdd(&s_cc[c], 1);
                    if(pos < CAP)
                        // key: (r desc, index asc); r>=0 so raw bits order as uint
                        s_ckey[c*CAP + pos] =
                            (((unsigned long long)__float_as_uint(rs[ia]))<<32) | (unsigned)(A_TOT - a);
                }
            }
            scnt += __popcll(__ballot(sure));
        }
        if(lane==0) s_chunk[ch] = scnt;           // wave owns chunk: exact, no atomic
    }
    __syncthreads();

    // ---- Phase D: rank boundary candidates (O(c^2), c is tens). -------------
    for(int c=0; c<2; ++c){
        int cc = s_cc[c]; if(cc > CAP) cc = CAP;
        int take = s_q[c*2+1];
        for(int i=tid; i<cc; i+=TT){
            unsigned long long ki = s_ckey[c*CAP + i];
            int rank = 0;
            for(int j=0;j<cc;++j) rank += (s_ckey[c*CAP + j] > ki) ? 1 : 0;
            if(rank < take){
                int ai = A_TOT - (int)(ki & 0xffffffffu);
                atomicOr(&s_bitmap[ai>>5], 1u << (ai & 31));
                atomicAdd(&s_chunk[ai>>8], 1);
            }
        }
    }
    __syncthreads();

    // ---- Phase E: chunk-base scan + defaults (reference zero-init scatter). --
    int v = 0;
    if(tid < 256){ v = (tid < NCHUNK) ? s_chunk[tid] : 0; s_scan[tid] = v; }
    __syncthreads();
    for(int off=1; off<256; off<<=1){
        int add = (tid<256 && tid>=off) ? s_scan[tid-off] : 0;
        __syncthreads();
        if(tid<256) s_scan[tid] += add;
        __syncthreads();
    }
    if(tid < NCHUNK) s_cbase[tid] = s_scan[tid] - v;
    if(tid < 256){
        int m0 = s_m0;
        int fg0 = (m0>>5)&1, bin0 = (m0>>7)&1023;
        // bitmap bit 0 only matters when fg0 (bg-class keep of anchor 0 => fg0==0)
        int k0b = (int)(s_bitmap[0] & 1u);
        float fgdef = (fg0 && ((bin0 > bs0) || k0b)) ? 1.0f : 0.0f;
        float4 a0 = ((const float4*)anchors)[0];
        float4 g0 = s_gt[m0 & 31];
        float cf0[4]; coeff_fn(a0, g0, cf0);
        out[n*TOTAL_K + tid] = 0.0f;
        out[(long)N_IMG*TOTAL_K + n*TOTAL_K + tid] = fgdef;
        for(int k=0;k<4;++k)
            out[(long)2*N_IMG*TOTAL_K + ((long)n*TOTAL_K + tid)*4 + k] = cf0[k];
    }
    __syncthreads();                              // defaults drained before emit

    // ---- Phase F: wave-per-chunk ballot compaction + emit (barrier-free,
    // ---- deterministic ascending-index slot order). -------------------------
    for(int ch=wave; ch<NCHUNK; ch+=NWAVE){
        int run = s_cbase[ch];
        for(int s=0; s<4; ++s){
            int a = ch*256 + s*64 + lane;
            long ia = (long)n*A_TOT + a;
            int f = flagsA[ia];
            int fg = (f>>5)&1;
            int bg = ((f>>6)&1) & !fg;
            int bin = (f>>7)&1023;
            int bit = (int)((s_bitmap[a>>5] >> (a&31)) & 1u);
            int kept = 0;
            if(fg)      kept = (bin > bs0) || bit;
            else if(bg) kept = (bin > bs1) || bit;
            unsigned long long mk = __ballot(kept);
            if(kept){
                int slot = run + __popcll(mk & ((1ull<<lane)-1ull));
                if(slot < TOTAL_K){
                    out[n*TOTAL_K + slot] = (float)a;
                    out[(long)N_IMG*TOTAL_K + n*TOTAL_K + slot] = fg ? 1.0f : 0.0f;
                    float4 aa = ((const float4*)anchors)[a];
                    float4 gg = s_gt[f & 31];
                    float cf[4]; coeff_fn(aa, gg, cf);
                    for(int k=0;k<4;++k)
                        out[(long)2*N_IMG*TOTAL_K + ((long)n*TOTAL_K + slot)*4 + k] = cf[k];
                }
            }
            run += __popcll(mk);
        }
    }
}

extern "C" void kernel_launch(void* const* d_in, const int* in_sizes, int n_in,
                              void* d_out, int out_size, void* d_ws, size_t ws_size,
                              hipStream_t stream){
    const float* anchors = (const float*)d_in[0];  // [36864,4]
    const float* gt      = (const float*)d_in[1];  // [32,32,4]
    const float* dl      = (const float*)d_in[2];  // [32,36864,4]
    const float* rs      = (const float*)d_in[3];  // [32,36864]
    float* out = (float*)d_out;                    // idx[32,256] | fg[32,256] | coeff[32,256,4]
    char* ws = (char*)d_ws;
    size_t off = 0;
    int* flagsA   = (int*)(ws + off); off += (size_t)N_IMG*A_TOT*4;        // 4,718,592
    int* bmax     = (int*)(ws + off); off += (size_t)N_IMG*NCHUNK*M_GT*4;  // 589,824
    int* pgm      = (int*)(ws + off); off += 4096;                         // NOT zeroed (atomicMax over poison)

    hipLaunchKernelGGL(k_main, dim3(N_IMG*NCHUNK), dim3(256), 0, stream,
                       anchors, gt, dl, rs, bmax, flagsA, pgm);
    hipLaunchKernelGGL(k_tail, dim3(N_IMG),        dim3(TT),  0, stream,
                       anchors, gt, dl, rs, bmax, pgm, flagsA, out);
}

// Round 2
// 171.800 us; speedup vs baseline: 1.2198x; 1.2198x over previous
//
#include <hip/hip_runtime.h>
#include <math.h>

#define A_TOT  36864
#define N_IMG  32
#define M_GT   32
#define TOTAL_K 256
#define MAX_FG_K 128
#define NCHUNK 144          // chunks (256 anchors) per image
#define CAP    1024
#define FGB    32
#define BGB    64
#define RAW_NEG1 ((int)0xBF800000u)   // __float_as_int(-1.0f)
#define RAW_P07  ((int)0x3F333333u)   // __float_as_int(0.7f)
#define RAW_P03  ((int)0x3E99999Au)   // __float_as_int(0.3f)
#define INT_MINV ((int)0x80000000u)
// IoU values live in {-1.0} ∪ [0,1]; signed-int compare of raw float bits ==
// float compare on that domain (no -0.0/NaN on the valid path).
// flags layout: bid[0:4] | fg<<5 | bg<<6 | bin<<7 (10b)
// (bg bit may stay set on fg-promoted anchors; consumers use bg & !fg)

__device__ __forceinline__ int bin_of(float r){
    int b = (int)(r * 1024.0f);
    return b > 1023 ? 1023 : (b < 0 ? 0 : b);
}

struct Pred { float x1,y1,x2,y2,area; int valid; };

__device__ __forceinline__ Pred mk_pred(float4 a, float4 d){
#pragma clang fp contract(off)
    Pred p;
    float w  = a.z - a.x + 1.0f;
    float h  = a.w - a.y + 1.0f;
    float cx = a.x + 0.5f*w;
    float cy = a.y + 0.5f*h;
    float pcx = d.x*w + cx;
    float pcy = d.y*h + cy;
    float pw = (float)exp((double)d.z) * w;
    float ph = (float)exp((double)d.w) * h;
    p.x1 = pcx - 0.5f*pw;
    p.y1 = pcy - 0.5f*ph;
    p.x2 = pcx + 0.5f*pw;
    p.y2 = pcy + 0.5f*ph;
    p.valid = (p.x1 >= 0.0f) && (p.y1 >= 0.0f) && (p.x2 < 1024.0f) && (p.y2 < 1024.0f);
    p.area  = (p.x2 - p.x1 + 1.0f) * (p.y2 - p.y1 + 1.0f);
    return p;
}

__device__ __forceinline__ float gt_area(float4 g){
#pragma clang fp contract(off)
    return (g.z - g.x + 1.0f) * (g.w - g.y + 1.0f);
}

__device__ __forceinline__ float iou_val(const Pred& p, float gx1, float gy1,
                                         float gx2, float gy2, float ga){
#pragma clang fp contract(off)
    float iw = fminf(p.x2,gx2) - fmaxf(p.x1,gx1) + 1.0f; iw = iw < 0.0f ? 0.0f : iw;
    float ih = fminf(p.y2,gy2) - fmaxf(p.y1,gy1) + 1.0f; ih = ih < 0.0f ? 0.0f : ih;
    float inter = iw * ih;
    float uni = (p.area + ga) - inter;
    float v = inter / uni;
    return p.valid ? v : -1.0f;
}

__device__ __forceinline__ void coeff_fn(float4 a, float4 g, float cf[4]){
#pragma clang fp contract(off)
    float aw = a.z - a.x + 1.0f, ah = a.w - a.y + 1.0f;
    float acx = a.x + 0.5f*aw,  acy = a.y + 0.5f*ah;
    float gw = g.z - g.x + 1.0f, gh = g.w - g.y + 1.0f;
    float gcx = g.x + 0.5f*gw,  gcy = g.y + 0.5f*gh;
    cf[0] = (gcx - acx) / aw;
    cf[1] = (gcy - acy) / ah;
    cf[2] = (float)log((double)(gw / aw));
    cf[3] = (float)log((double)(gh / ah));
}

// ---------- K1: heavy pass. Flags, bmax, pgm. Wave-uniform no-overlap skip:
// ---------- when no lane in the wave has iw>0&&ih>0, v is exactly +0.0 (valid)
// ---------- or -1.0 (invalid) — bit-identical to the division path (0/pos=+0).
// ---------- LDS atomicMax only for vi>0 (init -1; zero-chunk-max only differs
// ---------- in the degenerate all-zero-gt case, absent with dense anchors).
// ---------- Also zeroes hist for the next dispatch (ch<8 blocks). ------------
__global__ void k_main(const float* __restrict__ anchors, const float* __restrict__ gt,
                       const float* __restrict__ dl, const float* __restrict__ rs,
                       int* __restrict__ bmax, int* __restrict__ flagsA,
                       int* __restrict__ pgm, int* __restrict__ hist){
#pragma clang fp contract(off)
    int blk = blockIdx.x;
    int n = blk / NCHUNK, ch = blk % NCHUNK;
    int tid = threadIdx.x;
    int a = ch*256 + tid;
    __shared__ float4 sgt[M_GT];
    __shared__ float  sga[M_GT];
    __shared__ int    sbm[M_GT];
    if(ch < 8) hist[n*2048 + (ch<<8) + tid] = 0;     // consumed next dispatch
    if(tid < M_GT){
        float4 g = ((const float4*)gt)[n*M_GT + tid];
        sgt[tid] = g; sga[tid] = gt_area(g); sbm[tid] = RAW_NEG1;
    }
    __syncthreads();
    float4 anc = ((const float4*)anchors)[a];
    float4 d   = ((const float4*)dl)[(long)n*A_TOT + a];
    Pred p = mk_pred(anc, d);
    int beste = INT_MINV, bid = 0;
    int mm0 = tid & 31;
    #pragma unroll
    for(int j=0;j<M_GT;++j){
        int m = (mm0 + j) & 31;      // stagger: spreads LDS banks; tie-break below
        float4 g = sgt[m];
        float iw = fminf(p.x2,g.z) - fmaxf(p.x1,g.x) + 1.0f;
        float ih = fminf(p.y2,g.w) - fmaxf(p.y1,g.y) + 1.0f;
        bool hit = (iw > 0.0f) & (ih > 0.0f);
        int vi;
        if(__ballot(hit)){
            float cw  = iw < 0.0f ? 0.0f : iw;
            float chh = ih < 0.0f ? 0.0f : ih;
            float inter = cw * chh;
            float uni = (p.area + sga[m]) - inter;
            float v = inter / uni;          // non-hit valid lanes: 0/pos = +0.0 exact
            v = p.valid ? v : -1.0f;
            vi = __float_as_int(v);
        } else {
            vi = p.valid ? 0 : RAW_NEG1;    // bit-identical to division path
        }
        if(vi > 0) atomicMax(&sbm[m], vi);
        // rotated visit order => explicit (v desc, m asc) tie-break == first argmax
        if(vi > beste || (vi == beste && m < bid)){ beste = vi; bid = m; }
    }
    __syncthreads();
    long ia = (long)n*A_TOT + a;
    int bin = bin_of(rs[ia]);
    int thrfg = (beste >= RAW_P07) ? 1 : 0;
    int bg0 = (!thrfg) & (beste < RAW_P03 ? 1 : 0) & p.valid;
    flagsA[ia] = bid | (thrfg<<5) | (bg0<<6) | (bin<<7);
    if(tid < M_GT){
        bmax[blk*M_GT + tid] = sbm[tid];
        atomicMax(&pgm[n*M_GT + tid], sbm[tid]);   // poison 0xAAAAAAAA < raw(-1): no init needed
    }
}

// ---------- K2: per-chunk fix + histogram, 4608 blocks. Each block owns one
// ---------- chunk: promotes its own achievers (bmax row vs pgm => no cross-
// ---------- block flag writes), then histograms FINAL flags via global
// ---------- atomics (hist zeroed by k_main). blk 0 zeroes candcnt for K3. ----
__global__ void k_fixhist(const float* __restrict__ anchors, const float* __restrict__ gt,
                          const float* __restrict__ dl, const int* __restrict__ bmax,
                          const int* __restrict__ pgm, int* __restrict__ flagsA,
                          int* __restrict__ hist, int* __restrict__ candcnt){
    int blk = blockIdx.x;
    int n = blk / NCHUNK, ch = blk % NCHUNK;
    int tid = threadIdx.x;
    __shared__ float4 s_g[M_GT];
    __shared__ float  s_ga[M_GT];
    __shared__ int    s_t[M_GT];
    __shared__ int    s_nm;
    if(tid == 0) s_nm = 0;
    __syncthreads();
    if(tid < M_GT){
        int t = pgm[n*M_GT + tid];
        if(bmax[blk*M_GT + tid] == t){            // this chunk holds an achiever for gt tid
            int pos = atomicAdd(&s_nm, 1);
            float4 g = ((const float4*)gt)[n*M_GT + tid];
            s_g[pos] = g; s_ga[pos] = gt_area(g); s_t[pos] = t;
        }
    }
    __syncthreads();
    int nm = s_nm;                                 // block-uniform
    int a = ch*256 + tid;
    long ia = (long)n*A_TOT + a;
    int f = flagsA[ia];
    if(nm > 0){
        float4 anc = ((const float4*)anchors)[a];
        float4 d   = ((const float4*)dl)[ia];
        Pred p = mk_pred(anc, d);
        int f0 = f;
        for(int k=0;k<nm;++k){
            float4 g = s_g[k];
            float v = iou_val(p, g.x, g.y, g.z, g.w, s_ga[k]);
            if(p.valid && __float_as_int(v) == s_t[k]) f |= FGB;   // pgm>0 => achiever valid
        }
        if(f != f0) flagsA[ia] = f;
    }
    int fg = (f>>5)&1;
    int bg = ((f>>6)&1) & !fg;
    int bin = (f>>7)&1023;
    if(fg | bg) atomicAdd(&hist[n*2048 + (fg ? 0 : 1024) + bin], 1);
    if(blk == 0 && tid < 64) candcnt[tid] = 0;     // consumed next dispatch
}

// ---------- K3: inline per-block quota (redundant, hist is L2-hot) +
// ---------- sure-keeps, boundary candidates, chunk counts. ------------------
__global__ void k_bound(const int* __restrict__ flagsA, const float* __restrict__ rs,
                        const int* __restrict__ hist,
                        unsigned long long* __restrict__ cand, int* __restrict__ candcnt,
                        int* __restrict__ chunkcnt){
    int blk = blockIdx.x, tid = threadIdx.x;
    int n = blk / NCHUNK, ch = blk % NCHUNK;
    int wave = tid >> 6, lane = tid & 63;
    __shared__ int s_scan[256];
    __shared__ int s_q[4];
    __shared__ int s_wc[4];
    int fgK = 0;
    for(int phase=0; phase<2; ++phase){
        int b0 = 1023 - 4*tid;                              // bins b0..b0-3 desc
        int4 h4 = *(const int4*)&hist[n*2048 + phase*1024 + b0 - 3];
        int part = h4.x + h4.y + h4.z + h4.w;
        s_scan[tid] = part;
        __syncthreads();
        for(int off=1; off<256; off<<=1){
            int add = (tid>=off) ? s_scan[tid-off] : 0;
            __syncthreads();
            s_scan[tid] += add;
            __syncthreads();
        }
        int total = s_scan[255];
        if(tid==0){ s_q[phase*2] = -1; s_q[phase*2+1] = 0; }
        __syncthreads();
        int quota = (phase==0) ? MAX_FG_K : (TOTAL_K - fgK);
        if(total > quota){
            int pre = s_scan[tid] - part, cum = pre;
            int hs4[4] = {h4.w, h4.z, h4.y, h4.x};          // descending bin order
            for(int j=0;j<4;++j){
                int hh = hs4[j];
                if(cum < quota && cum + hh >= quota){ s_q[phase*2] = b0-j; s_q[phase*2+1] = quota-cum; }
                cum += hh;
            }
        }
        __syncthreads();
        if(phase==0) fgK = (total < MAX_FG_K) ? total : MAX_FG_K;
    }
    int bs0 = s_q[0], bs1 = s_q[2];
    int a = ch*256 + tid;
    long ia = (long)n*A_TOT + a;
    int f = flagsA[ia];
    int fg = (f>>5)&1;
    int bg = ((f>>6)&1) & !fg;
    int bin = (f>>7)&1023;
    int sure = 0;
    if(fg | bg){
        int c = fg ? 0 : 1;
        int bsel = fg ? bs0 : bs1;
        if(bin > bsel) sure = 1;                 // keepAll encoded as bsel=-1
        else if(bin == bsel){
            int pos = atomicAdd(&candcnt[n*2+c], 1);
            if(pos < CAP){
                // key: (r desc, index asc); r>=0 so raw bits order as uint
                cand[(n*2+c)*CAP + pos] =
                    (((unsigned long long)__float_as_uint(rs[ia]))<<32) | (unsigned)(A_TOT - a);
            }
        }
    }
    unsigned long long mk = __ballot(sure);
    if(lane==0) s_wc[wave] = __popcll(mk);
    __syncthreads();
    if(tid==0) chunkcnt[n*NCHUNK + ch] = s_wc[0]+s_wc[1]+s_wc[2]+s_wc[3];
}

// ---------- K4: absorbs k_rank. Each of 4608 blocks redundantly computes
// ---------- quota (L2-hot hist) + ranks the tiny candidate list (O(c^2),
// ---------- c~tens), accumulates rank-keep extras per chunk in LDS, inline
// ---------- prefix over 144 chunk counts, ballot-compacts its own chunk.
// ---------- ch==0 block writes defaults only to slots >= T (disjoint). ------
__global__ __launch_bounds__(256) void k_out(const float* __restrict__ anchors,
        const float* __restrict__ gt, const int* __restrict__ flagsA,
        const int* __restrict__ hist, const int* __restrict__ candcnt,
        const unsigned long long* __restrict__ cand,
        const int* __restrict__ chunkcnt, float* __restrict__ out){
    int blk = blockIdx.x, tid = threadIdx.x;
    int n = blk / NCHUNK, ch = blk % NCHUNK;
    int wave = tid >> 6, lane = tid & 63;
    __shared__ unsigned long long s_ckey[CAP];   // 8 KB, reused per class
    __shared__ int s_scan[256];
    __shared__ int s_q[4];
    __shared__ int s_cex[NCHUNK];                // rank-keep extras per chunk
    __shared__ unsigned int s_keep[8];           // own-chunk keep bits
    __shared__ int s_wc[4];
    for(int i=tid; i<NCHUNK; i+=256) s_cex[i] = 0;
    if(tid < 8) s_keep[tid] = 0u;
    // ---- quota (identical code/data to k_bound => identical result) ----
    int fgK = 0;
    for(int phase=0; phase<2; ++phase){
        int b0 = 1023 - 4*tid;
        int4 h4 = *(const int4*)&hist[n*2048 + phase*1024 + b0 - 3];
        int part = h4.x + h4.y + h4.z + h4.w;
        s_scan[tid] = part;
        __syncthreads();
        for(int off=1; off<256; off<<=1){
            int add = (tid>=off) ? s_scan[tid-off] : 0;
            __syncthreads();
            s_scan[tid] += add;
            __syncthreads();
        }
        int total = s_scan[255];
        if(tid==0){ s_q[phase*2] = -1; s_q[phase*2+1] = 0; }
        __syncthreads();
        int quota = (phase==0) ? MAX_FG_K : (TOTAL_K - fgK);
        if(total > quota){
            int pre = s_scan[tid] - part, cum = pre;
            int hs4[4] = {h4.w, h4.z, h4.y, h4.x};
            for(int j=0;j<4;++j){
                int hh = hs4[j];
                if(cum < quota && cum + hh >= quota){ s_q[phase*2] = b0-j; s_q[phase*2+1] = quota-cum; }
                cum += hh;
            }
        }
        __syncthreads();
        if(phase==0) fgK = (total < MAX_FG_K) ? total : MAX_FG_K;
    }
    int bs0 = s_q[0], bs1 = s_q[2];
    // ---- redundant rank of boundary candidates (deterministic: same data) ----
    for(int c=0; c<2; ++c){
        int cc = candcnt[n*2+c]; if(cc > CAP) cc = CAP;
        int take = s_q[c*2+1];
        for(int i=tid; i<cc; i+=256) s_ckey[i] = cand[(n*2+c)*CAP + i];
        __syncthreads();
        for(int i=tid; i<cc; i+=256){
            unsigned long long ki = s_ckey[i];
            int rank = 0;
            for(int j=0;j<cc;++j) rank += (s_ckey[j] > ki) ? 1 : 0;
            if(rank < take){
                int ai = A_TOT - (int)(ki & 0xffffffffu);
                atomicAdd(&s_cex[ai>>8], 1);
                if((ai>>8) == ch) atomicOr(&s_keep[(ai&255)>>5], 1u << (ai & 31));
            }
        }
        __syncthreads();
    }
    // ---- chunk-base prefix (144 L2-hot ints + LDS extras) ----
    int v = (tid < NCHUNK) ? chunkcnt[n*NCHUNK + tid] + s_cex[tid] : 0;
    s_scan[tid] = v;
    __syncthreads();
    for(int off=1; off<256; off<<=1){
        int add = (tid>=off) ? s_scan[tid-off] : 0;
        __syncthreads();
        s_scan[tid] += add;
        __syncthreads();
    }
    int T = s_scan[255];                          // total kept (<= 256)
    int base = (ch > 0) ? s_scan[ch-1] : 0;
    // ---- emit own chunk ----
    int a = ch*256 + tid;
    long ia = (long)n*A_TOT + a;
    int f = flagsA[ia];
    int fg = (f>>5)&1;
    int bg = ((f>>6)&1) & !fg;
    int bin = (f>>7)&1023;
    int bit = (int)((s_keep[tid>>5] >> (tid&31)) & 1u);
    int kept = 0;
    if(fg)      kept = (bin > bs0) || bit;
    else if(bg) kept = (bin > bs1) || bit;
    unsigned long long mk = __ballot(kept);
    if(lane==0) s_wc[wave] = __popcll(mk);
    __syncthreads();
    if(kept){
        int slot = base;
        for(int w=0; w<wave; ++w) slot += s_wc[w];
        slot += __popcll(mk & ((1ull<<lane)-1ull));
        if(slot < TOTAL_K){
            out[n*TOTAL_K + slot] = (float)a;
            out[(long)N_IMG*TOTAL_K + n*TOTAL_K + slot] = fg ? 1.0f : 0.0f;
            float4 aa = ((const float4*)anchors)[a];
            float4 gg = ((const float4*)gt)[n*M_GT + (f & 31)];
            float cf[4]; coeff_fn(aa, gg, cf);
            for(int k=0;k<4;++k)
                out[(long)2*N_IMG*TOTAL_K + ((long)n*TOTAL_K + slot)*4 + k] = cf[k];
        }
    }
    // ---- defaults: padding slots [T,256) behave like anchor 0 (reference
    // ---- zero-init scatter). Disjoint from all emission slots (<T). ----
    if(ch == 0 && tid >= T){
        int m0 = flagsA[(long)n*A_TOT];           // L1-hot, post-fix
        int fg0 = (m0>>5)&1, bin0 = (m0>>7)&1023;
        int k0b = (int)(s_keep[0] & 1u);          // only matters when fg0 set
        float fgdef = (fg0 && ((bin0 > bs0) || k0b)) ? 1.0f : 0.0f;
        float4 a0 = ((const float4*)anchors)[0];
        float4 g0 = ((const float4*)gt)[n*M_GT + (m0 & 31)];
        float cf0[4]; coeff_fn(a0, g0, cf0);
        out[n*TOTAL_K + tid] = 0.0f;
        out[(long)N_IMG*TOTAL_K + n*TOTAL_K + tid] = fgdef;
        for(int k=0;k<4;++k)
            out[(long)2*N_IMG*TOTAL_K + ((long)n*TOTAL_K + tid)*4 + k] = cf0[k];
    }
}

extern "C" void kernel_launch(void* const* d_in, const int* in_sizes, int n_in,
                              void* d_out, int out_size, void* d_ws, size_t ws_size,
                              hipStream_t stream){
    const float* anchors = (const float*)d_in[0];  // [36864,4]
    const float* gt      = (const float*)d_in[1];  // [32,32,4]
    const float* dl      = (const float*)d_in[2];  // [32,36864,4]
    const float* rs      = (const float*)d_in[3];  // [32,36864]
    float* out = (float*)d_out;                    // idx[32,256] | fg[32,256] | coeff[32,256,4]
    char* ws = (char*)d_ws;
    size_t off = 0;
    int* flagsA   = (int*)(ws + off); off += (size_t)N_IMG*A_TOT*4;        // 4,718,592
    int* bmax     = (int*)(ws + off); off += (size_t)N_IMG*NCHUNK*M_GT*4;  // 589,824
    int* pgm      = (int*)(ws + off); off += 4096;                         // NOT zeroed (atomicMax over poison)
    int* hist     = (int*)(ws + off); off += (size_t)N_IMG*2048*4;         // zeroed by k_main
    int* candcnt  = (int*)(ws + off); off += 256;                          // zeroed by k_fixhist blk0
    unsigned long long* cand = (unsigned long long*)(ws + off); off += (size_t)N_IMG*2*CAP*8;
    int* chunkcnt = (int*)(ws + off); off += (size_t)N_IMG*NCHUNK*4;

    hipLaunchKernelGGL(k_main,    dim3(N_IMG*NCHUNK), dim3(256), 0, stream,
                       anchors, gt, dl, rs, bmax, flagsA, pgm, hist);
    hipLaunchKernelGGL(k_fixhist, dim3(N_IMG*NCHUNK), dim3(256), 0, stream,
                       anchors, gt, dl, bmax, pgm, flagsA, hist, candcnt);
    hipLaunchKernelGGL(k_bound,   dim3(N_IMG*NCHUNK), dim3(256), 0, stream,
                       flagsA, rs, hist, cand, candcnt, chunkcnt);
    hipLaunchKernelGGL(k_out,     dim3(N_IMG*NCHUNK), dim3(256), 0, stream,
                       anchors, gt, flagsA, hist, candcnt, cand, chunkcnt, out);
}